// Round 17
// baseline (55.721 us; speedup 1.0000x reference)
//
#include <hip/hip_runtime.h>
#include <hip/hip_bf16.h>
#include <math.h>

#define C1F  0.577078016f   // 0.4 * log2(e)
#define C2F  0.865617024f   // 0.6 * log2(e)

// ws byte offsets
#define WS_CNT 0                          // 16 x i64
#define WS_AGG 128                        // 1024 x i64  (ends 8320)
#define WS_G   8320                       // g2[4][16][2048] f32 (524288 B)
#define WS_DCL (8320 + 524288)            // dclT[4][2048] f32 (ends 573056)

typedef float __attribute__((ext_vector_type(4))) f32x4;

__device__ __forceinline__ float rfl(float x) {
    return __uint_as_float(__builtin_amdgcn_readfirstlane(__float_as_uint(x)));
}

__device__ __forceinline__ unsigned lds_addr(const void* p) {
    return (unsigned)(unsigned long long)
        (__attribute__((address_space(3))) const char*)p;
}

// pinned LDS read: asm result regs cannot be rematerialized -> G stays live
#define DSR(dst, a, lit) \
    asm volatile("ds_read_b128 %0, %1 offset:" lit : "=v"(dst) : "v"(a))

// full wave64 sum via DPP (no DS pipe); total valid in lane 63.
__device__ __forceinline__ float dpp_sum(float x) {
    float y;
    y = __int_as_float(__builtin_amdgcn_update_dpp(0, __float_as_int(x), 0x111, 0xf, 0xf, true)); x += y;
    y = __int_as_float(__builtin_amdgcn_update_dpp(0, __float_as_int(x), 0x112, 0xf, 0xf, true)); x += y;
    y = __int_as_float(__builtin_amdgcn_update_dpp(0, __float_as_int(x), 0x114, 0xf, 0xf, true)); x += y;
    y = __int_as_float(__builtin_amdgcn_update_dpp(0, __float_as_int(x), 0x118, 0xf, 0xf, true)); x += y;
    y = __int_as_float(__builtin_amdgcn_update_dpp(0, __float_as_int(x), 0x142, 0xa, 0xf, true)); x += y;
    y = __int_as_float(__builtin_amdgcn_update_dpp(0, __float_as_int(x), 0x143, 0xc, 0xf, true)); x += y;
    return x;
}

// ---------------------------------------------------------------------------
// k_proj: ohm fill + g2[h][f][j] = (pin @ Wl^T)^T + dclT[h][i] + label cnt
// ---------------------------------------------------------------------------
__global__ __launch_bounds__(256) void k_proj(
    const float* __restrict__ x, const float* __restrict__ ohm,
    const float* __restrict__ Wl, const float* __restrict__ Wattn,
    unsigned char* __restrict__ ws)
{
    float* g2   = (float*)(ws + WS_G);
    float* dclT = (float*)(ws + WS_DCL);
    unsigned long long* cnt = (unsigned long long*)(ws + WS_CNT);

    int t = threadIdx.x;
    int r = blockIdx.x * 4 + (t >> 6);
    int o = t & 63;

    f32x4 oh[4]; float rs = 0.f;
    const f32x4* ohp = (const f32x4*)&ohm[r*16];
    #pragma unroll
    for (int q = 0; q < 4; ++q) { oh[q] = ohp[q]; rs += oh[q][0]+oh[q][1]+oh[q][2]+oh[q][3]; }
    if (rs == 0.f) {
        f32x4 c = {0.0625f, 0.0625f, 0.0625f, 0.0625f};
        #pragma unroll
        for (int q = 0; q < 4; ++q) oh[q] = c;
    }

    float acc = 0.f;
    const f32x4* xp = (const f32x4*)&x[r*64];
    const f32x4* wp = (const f32x4*)&Wl[o*80];
    #pragma unroll
    for (int q = 0; q < 16; ++q) {
        f32x4 a = xp[q], b = wp[q];
        acc = fmaf(a[0],b[0],acc); acc = fmaf(a[1],b[1],acc);
        acc = fmaf(a[2],b[2],acc); acc = fmaf(a[3],b[3],acc);
    }
    #pragma unroll
    for (int q = 0; q < 4; ++q) {
        f32x4 b = wp[16+q];
        acc = fmaf(oh[q][0],b[0],acc); acc = fmaf(oh[q][1],b[1],acc);
        acc = fmaf(oh[q][2],b[2],acc); acc = fmaf(oh[q][3],b[3],acc);
    }
    // transposed store: g2[h][f][j]
    g2[(o >> 4)*32768 + (o & 15)*2048 + r] = acc;

    float dot = Wattn[o & 15] * acc;
    #pragma unroll
    for (int m2 = 1; m2 < 16; m2 <<= 1) dot += __shfl_xor(dot, m2);
    if ((o & 15) == 0) dclT[(o >> 4)*2048 + r] = C2F * dot;

    if (t < 16) {  // exact label counts, fixed-point 2^20 (ohm in {0,1,1/16})
        float c = 0.f;
        for (int rr = 0; rr < 4; ++rr) {
            int r2 = blockIdx.x*4 + rr; float s = 0.f;
            #pragma unroll
            for (int k = 0; k < 16; ++k) s += ohm[r2*16+k];
            c += (s == 0.f) ? 0.0625f : ohm[r2*16+t];
        }
        atomicAdd(&cnt[t], (unsigned long long)__float2ll_rn(c * 1048576.0f));
    }
}

// ---------------------------------------------------------------------------
// k_attn: whole-head LDS residency, zero main-loop barriers. grid 256 x 1024.
// block = (head h = bid>>6, 32 rows). g2[h] (128KB) + dclT[h] (8KB) staged
// into LDS once. G[16] loaded via PINNED asm ds_read_b128 (compiler cannot
// re-read or rematerialize asm results) -> one DS touch per G element.
// ---------------------------------------------------------------------------
__global__ __launch_bounds__(1024, 1) void k_attn(
    const float* __restrict__ ohm, const float* __restrict__ Wattn,
    unsigned char* __restrict__ ws, float* __restrict__ hout)
{
    float* g2   = (float*)(ws + WS_G);
    float* dclT = (float*)(ws + WS_DCL);
    unsigned long long* agg = (unsigned long long*)(ws + WS_AGG);

    __shared__ float g2l[16*2048];   // 131,072 B  (f-major, stride-1 in j)
    __shared__ float djl[2048];      //   8,192 B
    __shared__ float shh[32*16];     //   2,048 B
    __shared__ float ohmf[32*16];    //   2,048 B  -> 143,360 B total

    int t = threadIdx.x, bid = blockIdx.x;
    int h  = bid >> 6;           // 4 heads x 64 row-groups
    int ib = (bid & 63) * 32;    // first of 32 rows
    int wid = t >> 6, l = t & 63;
    int i0 = ib + wid*2, i1 = i0 + 1;

    const float* g2h = g2 + h*32768;
    const float* dph = dclT + h*2048;

    // ---- stage whole head into LDS (coalesced), plus SGPR constants ----
    {
        const f32x4* s4 = (const f32x4*)g2h;
        f32x4* d4 = (f32x4*)g2l;
        #pragma unroll
        for (int c = 0; c < 8; ++c) d4[t + c*1024] = s4[t + c*1024];
        if (t < 512) ((f32x4*)djl)[t] = ((const f32x4*)dph)[t];
    }
    float wv[16], gA0[16], gA1[16];
    #pragma unroll
    for (int f = 0; f < 16; ++f) {
        wv[f]  = rfl(Wattn[f]);
        gA0[f] = rfl(g2h[f*2048 + i0]);
        gA1[f] = rfl(g2h[f*2048 + i1]);
    }
    __syncthreads();   // the only pre-epilogue barrier

    float acc0[16], acc1[16];
    float l0 = 0.f, l1 = 0.f;
    #pragma unroll
    for (int f = 0; f < 16; ++f) { acc0[f] = 0.f; acc1[f] = 0.f; }

    unsigned abase = lds_addr(&g2l[4*l]);      // + pass*1024 per pass
    unsigned dbase = lds_addr(&djl[4*l]);

    #pragma unroll 1
    for (int pass = 0; pass < 8; ++pass) {
        unsigned ap  = abase + pass*1024;
        unsigned ap2 = ap + 65536;             // f = 8..15 block
        f32x4 dj;
        DSR(dj, dbase + pass*1024, "0");
        f32x4 G[16];
        DSR(G[ 0], ap , "0");     DSR(G[ 1], ap , "8192");
        DSR(G[ 2], ap , "16384"); DSR(G[ 3], ap , "24576");
        DSR(G[ 4], ap , "32768"); DSR(G[ 5], ap , "40960");
        DSR(G[ 6], ap , "49152"); DSR(G[ 7], ap , "57344");
        DSR(G[ 8], ap2, "0");     DSR(G[ 9], ap2, "8192");
        DSR(G[10], ap2, "16384"); DSR(G[11], ap2, "24576");
        DSR(G[12], ap2, "32768"); DSR(G[13], ap2, "40960");
        DSR(G[14], ap2, "49152"); DSR(G[15], ap2, "57344");
        asm volatile("s_waitcnt lgkmcnt(0)" ::: "memory");
        __builtin_amdgcn_sched_barrier(0);     // rule 18: fence consumers

        float e00=0.f,e01=0.f,e02=0.f,e03=0.f;
        float e10=0.f,e11=0.f,e12=0.f,e13=0.f;
        #pragma unroll
        for (int f = 0; f < 16; ++f) {
            float a0 = gA0[f], a1 = gA1[f];
            f32x4 gf = G[f];
            e00 = fmaf(wv[f], fabsf(a0 + gf[0]), e00);   // |.| = free VOP3 mod
            e01 = fmaf(wv[f], fabsf(a0 + gf[1]), e01);
            e02 = fmaf(wv[f], fabsf(a0 + gf[2]), e02);
            e03 = fmaf(wv[f], fabsf(a0 + gf[3]), e03);
            e10 = fmaf(wv[f], fabsf(a1 + gf[0]), e10);
            e11 = fmaf(wv[f], fabsf(a1 + gf[1]), e11);
            e12 = fmaf(wv[f], fabsf(a1 + gf[2]), e12);
            e13 = fmaf(wv[f], fabsf(a1 + gf[3]), e13);
        }
        float p00 = __builtin_amdgcn_exp2f(fmaf(C1F, e00, dj[0]));
        float p01 = __builtin_amdgcn_exp2f(fmaf(C1F, e01, dj[1]));
        float p02 = __builtin_amdgcn_exp2f(fmaf(C1F, e02, dj[2]));
        float p03 = __builtin_amdgcn_exp2f(fmaf(C1F, e03, dj[3]));
        float p10 = __builtin_amdgcn_exp2f(fmaf(C1F, e10, dj[0]));
        float p11 = __builtin_amdgcn_exp2f(fmaf(C1F, e11, dj[1]));
        float p12 = __builtin_amdgcn_exp2f(fmaf(C1F, e12, dj[2]));
        float p13 = __builtin_amdgcn_exp2f(fmaf(C1F, e13, dj[3]));
        l0 += (p00 + p01) + (p02 + p03);
        l1 += (p10 + p11) + (p12 + p13);
        #pragma unroll
        for (int f = 0; f < 16; ++f) {
            f32x4 gf = G[f];
            acc0[f] = fmaf(p00, gf[0], fmaf(p01, gf[1],
                      fmaf(p02, gf[2], fmaf(p03, gf[3], acc0[f]))));
            acc1[f] = fmaf(p10, gf[0], fmaf(p11, gf[1],
                      fmaf(p12, gf[2], fmaf(p13, gf[3], acc1[f]))));
        }
    }

    // full-wave DPP reduction -> lane 63; each (row,head) owned by ONE wave
    float ls0 = dpp_sum(l0), ls1 = dpp_sum(l1);
    float h0[16], h1[16];
    #pragma unroll
    for (int f = 0; f < 16; ++f) { h0[f] = dpp_sum(acc0[f]); h1[f] = dpp_sum(acc1[f]); }

    if (l == 63) {
        float r0 = 1.0f / ls0, r1 = 1.0f / ls1;
        #pragma unroll
        for (int f = 0; f < 16; ++f) {
            float a = h0[f]*r0; a = fmaxf(a, 0.2f*a);
            float b = h1[f]*r1; b = fmaxf(b, 0.2f*b);
            hout[i0*64 + h*16 + f] = a;
            hout[i1*64 + h*16 + f] = b;
            shh[(wid*2    )*16 + f] = a;
            shh[(wid*2 + 1)*16 + f] = b;
        }
    }
    if (t < 512) {   // filled ohm for the block's 32 rows
        int r = t >> 4, lab = t & 15;
        float v = ohm[(ib + r)*16 + lab];
        float s = v;
        #pragma unroll
        for (int m2 = 1; m2 < 16; m2 <<= 1) s += __shfl_xor(s, m2);
        ohmf[r*16 + lab] = (s == 0.f) ? 0.0625f : v;
    }
    __syncthreads();

    // deterministic centroid partial agg for this block's (32 rows, 16 dims)
    if (t < 256) {
        int lab = t >> 4, dq = t & 15;
        float s = 0.f;
        #pragma unroll 8
        for (int r = 0; r < 32; ++r)
            s = fmaf(ohmf[r*16 + lab], shh[r*16 + dq], s);
        atomicAdd(&agg[lab*64 + h*16 + dq],
                  (unsigned long long)__float2ll_rn(s * 67108864.0f));
    }
}

// ---------------------------------------------------------------------------
// k_scores: rebuild centroids per block from agg/cnt, then cdist.
// ---------------------------------------------------------------------------
__global__ __launch_bounds__(256) void k_scores(
    unsigned char* __restrict__ ws, const float* __restrict__ hout,
    float* __restrict__ scores, float* __restrict__ missing)
{
    __shared__ float cl[16*68];
    unsigned long long* cnt = (unsigned long long*)(ws + WS_CNT);
    unsigned long long* agg = (unsigned long long*)(ws + WS_AGG);
    int t = threadIdx.x;

    for (int v = t; v < 1024; v += 256) {
        int ll = v >> 6, d = v & 63;
        long long a = (long long)agg[v];
        long long c = (long long)cnt[ll];
        cl[ll*68 + d] = (c == 0) ? 0.f : ((float)a / (float)c) * 0.015625f;
    }
    if (blockIdx.x == 0 && t < 16) missing[t] = (cnt[t] == 0) ? 1.0f : 0.0f;
    __syncthreads();

    int i = blockIdx.x*16 + (t >> 4), ll = t & 15;
    float s = 0.f;
    #pragma unroll 16
    for (int d = 0; d < 64; ++d) {
        float diff = hout[i*64 + d] - cl[ll*68 + d];
        s = fmaf(diff, diff, s);
    }
    scores[i*16 + ll] = -sqrtf(s);
}

// ---------------------------------------------------------------------------
extern "C" void kernel_launch(void* const* d_in, const int* in_sizes, int n_in,
                              void* d_out, int out_size, void* d_ws, size_t ws_size,
                              hipStream_t stream)
{
    const float* x     = (const float*)d_in[0];
    const float* ohm   = (const float*)d_in[1];
    const float* Wl    = (const float*)d_in[2];
    const float* Wattn = (const float*)d_in[3];
    unsigned char* ws  = (unsigned char*)d_ws;

    float* out     = (float*)d_out;
    float* scores  = out;
    float* hout    = out + 2048*16;
    float* missing = out + 2048*16 + 2048*64;

    hipMemsetAsync(d_ws, 0, 8320, stream);           // cnt + agg
    k_proj  <<<512, 256, 0, stream>>>(x, ohm, Wl, Wattn, ws);
    k_attn  <<<256, 1024, 0, stream>>>(ohm, Wattn, ws, hout);
    k_scores<<<128, 256, 0, stream>>>(ws, hout, scores, missing);
}

// Round 20
// 54.742 us; speedup vs baseline: 1.0179x; 1.0179x over previous
//
#include <hip/hip_runtime.h>
#include <hip/hip_bf16.h>
#include <math.h>

#define C1F  0.577078016f   // 0.4 * log2(e)
#define C2F  0.865617024f   // 0.6 * log2(e)

// ws byte offsets
#define WS_CNT 0                          // 16 x i64
#define WS_AGG 128                        // 1024 x i64  (ends 8320)
#define WS_G   8320                       // g2[4][16][2048] f32 (524288 B)
#define WS_DCL (8320 + 524288)            // dclT[4][2048] f32 (ends 573056)

typedef float __attribute__((ext_vector_type(4))) f32x4;

__device__ __forceinline__ float rfl(float x) {
    return __uint_as_float(__builtin_amdgcn_readfirstlane(__float_as_uint(x)));
}

// full wave64 sum via DPP (no DS pipe); total valid in lane 63.
__device__ __forceinline__ float dpp_sum(float x) {
    float y;
    y = __int_as_float(__builtin_amdgcn_update_dpp(0, __float_as_int(x), 0x111, 0xf, 0xf, true)); x += y;
    y = __int_as_float(__builtin_amdgcn_update_dpp(0, __float_as_int(x), 0x112, 0xf, 0xf, true)); x += y;
    y = __int_as_float(__builtin_amdgcn_update_dpp(0, __float_as_int(x), 0x114, 0xf, 0xf, true)); x += y;
    y = __int_as_float(__builtin_amdgcn_update_dpp(0, __float_as_int(x), 0x118, 0xf, 0xf, true)); x += y;
    y = __int_as_float(__builtin_amdgcn_update_dpp(0, __float_as_int(x), 0x142, 0xa, 0xf, true)); x += y;
    y = __int_as_float(__builtin_amdgcn_update_dpp(0, __float_as_int(x), 0x143, 0xc, 0xf, true)); x += y;
    return x;
}

// ---------------------------------------------------------------------------
// k_proj: ohm fill + g2[h][f][j] = (pin @ Wl^T)^T + dclT[h][i] + label cnt
// ---------------------------------------------------------------------------
__global__ __launch_bounds__(256) void k_proj(
    const float* __restrict__ x, const float* __restrict__ ohm,
    const float* __restrict__ Wl, const float* __restrict__ Wattn,
    unsigned char* __restrict__ ws)
{
    float* g2   = (float*)(ws + WS_G);
    float* dclT = (float*)(ws + WS_DCL);
    unsigned long long* cnt = (unsigned long long*)(ws + WS_CNT);

    int t = threadIdx.x;
    int r = blockIdx.x * 4 + (t >> 6);
    int o = t & 63;

    f32x4 oh[4]; float rs = 0.f;
    const f32x4* ohp = (const f32x4*)&ohm[r*16];
    #pragma unroll
    for (int q = 0; q < 4; ++q) { oh[q] = ohp[q]; rs += oh[q][0]+oh[q][1]+oh[q][2]+oh[q][3]; }
    if (rs == 0.f) {
        f32x4 c = {0.0625f, 0.0625f, 0.0625f, 0.0625f};
        #pragma unroll
        for (int q = 0; q < 4; ++q) oh[q] = c;
    }

    float acc = 0.f;
    const f32x4* xp = (const f32x4*)&x[r*64];
    const f32x4* wp = (const f32x4*)&Wl[o*80];
    #pragma unroll
    for (int q = 0; q < 16; ++q) {
        f32x4 a = xp[q], b = wp[q];
        acc = fmaf(a[0],b[0],acc); acc = fmaf(a[1],b[1],acc);
        acc = fmaf(a[2],b[2],acc); acc = fmaf(a[3],b[3],acc);
    }
    #pragma unroll
    for (int q = 0; q < 4; ++q) {
        f32x4 b = wp[16+q];
        acc = fmaf(oh[q][0],b[0],acc); acc = fmaf(oh[q][1],b[1],acc);
        acc = fmaf(oh[q][2],b[2],acc); acc = fmaf(oh[q][3],b[3],acc);
    }
    // transposed store: g2[h][f][j]
    g2[(o >> 4)*32768 + (o & 15)*2048 + r] = acc;

    float dot = Wattn[o & 15] * acc;
    #pragma unroll
    for (int m2 = 1; m2 < 16; m2 <<= 1) dot += __shfl_xor(dot, m2);
    if ((o & 15) == 0) dclT[(o >> 4)*2048 + r] = C2F * dot;

    if (t < 16) {  // exact label counts, fixed-point 2^20 (ohm in {0,1,1/16})
        float c = 0.f;
        for (int rr = 0; rr < 4; ++rr) {
            int r2 = blockIdx.x*4 + rr; float s = 0.f;
            #pragma unroll
            for (int k = 0; k < 16; ++k) s += ohm[r2*16+k];
            c += (s == 0.f) ? 0.0625f : ohm[r2*16+t];
        }
        atomicAdd(&cnt[t], (unsigned long long)__float2ll_rn(c * 1048576.0f));
    }
}

// ---------------------------------------------------------------------------
// k_attn: whole-head LDS residency, zero main-loop barriers. grid 256 x 1024.
// block = (head h = bid>>6, 32 rows). g2[h] (128KB) + dclT[h] (8KB) in LDS.
// r16 structure + WAVE-STAGGERED pass order: wave w processes pass
// (pass + w) & 7, so DS bursts of the 16 waves are spread in time and the
// DS pipe overlaps other waves' VALU instead of convoy-alternating.
// Pass order is irrelevant to the math (fixed-shift sums, no running max).
// ---------------------------------------------------------------------------
__global__ __launch_bounds__(1024, 1) void k_attn(
    const float* __restrict__ ohm, const float* __restrict__ Wattn,
    unsigned char* __restrict__ ws, float* __restrict__ hout)
{
    float* g2   = (float*)(ws + WS_G);
    float* dclT = (float*)(ws + WS_DCL);
    unsigned long long* agg = (unsigned long long*)(ws + WS_AGG);

    __shared__ float g2l[16*2048];   // 131,072 B  (f-major, stride-1 in j)
    __shared__ float djl[2048];      //   8,192 B
    __shared__ float shh[32*16];     //   2,048 B
    __shared__ float ohmf[32*16];    //   2,048 B  -> 143,360 B total

    int t = threadIdx.x, bid = blockIdx.x;
    int h  = bid >> 6;           // 4 heads x 64 row-groups
    int ib = (bid & 63) * 32;    // first of 32 rows
    int wid = t >> 6, l = t & 63;
    int i0 = ib + wid*2, i1 = i0 + 1;

    const float* g2h = g2 + h*32768;
    const float* dph = dclT + h*2048;

    // ---- stage whole head into LDS (coalesced), plus SGPR constants ----
    {
        const f32x4* s4 = (const f32x4*)g2h;
        f32x4* d4 = (f32x4*)g2l;
        #pragma unroll
        for (int c = 0; c < 8; ++c) d4[t + c*1024] = s4[t + c*1024];
        if (t < 512) ((f32x4*)djl)[t] = ((const f32x4*)dph)[t];
    }
    float wv[16], gA0[16], gA1[16];
    #pragma unroll
    for (int f = 0; f < 16; ++f) {
        wv[f]  = rfl(Wattn[f]);
        gA0[f] = rfl(g2h[f*2048 + i0]);
        gA1[f] = rfl(g2h[f*2048 + i1]);
    }
    __syncthreads();   // the only pre-epilogue barrier

    float acc0[16], acc1[16];
    float l0 = 0.f, l1 = 0.f;
    #pragma unroll
    for (int f = 0; f < 16; ++f) { acc0[f] = 0.f; acc1[f] = 0.f; }

    #pragma unroll 1
    for (int pass = 0; pass < 8; ++pass) {
        int pp = (pass + wid) & 7;           // per-wave rotation (desync)
        int jb = pp*256 + 4*l;
        f32x4 G[16];
        #pragma unroll
        for (int f = 0; f < 16; ++f) G[f] = *(const f32x4*)&g2l[f*2048 + jb];
        f32x4 dj = *(const f32x4*)&djl[jb];

        float e00=0.f,e01=0.f,e02=0.f,e03=0.f;
        float e10=0.f,e11=0.f,e12=0.f,e13=0.f;
        #pragma unroll
        for (int f = 0; f < 16; ++f) {
            float a0 = gA0[f], a1 = gA1[f];
            f32x4 gf = G[f];
            e00 = fmaf(wv[f], fabsf(a0 + gf[0]), e00);   // |.| = free VOP3 mod
            e01 = fmaf(wv[f], fabsf(a0 + gf[1]), e01);
            e02 = fmaf(wv[f], fabsf(a0 + gf[2]), e02);
            e03 = fmaf(wv[f], fabsf(a0 + gf[3]), e03);
            e10 = fmaf(wv[f], fabsf(a1 + gf[0]), e10);
            e11 = fmaf(wv[f], fabsf(a1 + gf[1]), e11);
            e12 = fmaf(wv[f], fabsf(a1 + gf[2]), e12);
            e13 = fmaf(wv[f], fabsf(a1 + gf[3]), e13);
        }
        float p00 = __builtin_amdgcn_exp2f(fmaf(C1F, e00, dj[0]));
        float p01 = __builtin_amdgcn_exp2f(fmaf(C1F, e01, dj[1]));
        float p02 = __builtin_amdgcn_exp2f(fmaf(C1F, e02, dj[2]));
        float p03 = __builtin_amdgcn_exp2f(fmaf(C1F, e03, dj[3]));
        float p10 = __builtin_amdgcn_exp2f(fmaf(C1F, e10, dj[0]));
        float p11 = __builtin_amdgcn_exp2f(fmaf(C1F, e11, dj[1]));
        float p12 = __builtin_amdgcn_exp2f(fmaf(C1F, e12, dj[2]));
        float p13 = __builtin_amdgcn_exp2f(fmaf(C1F, e13, dj[3]));
        l0 += (p00 + p01) + (p02 + p03);
        l1 += (p10 + p11) + (p12 + p13);
        #pragma unroll
        for (int f = 0; f < 16; ++f) {
            f32x4 gf = G[f];
            acc0[f] = fmaf(p00, gf[0], fmaf(p01, gf[1],
                      fmaf(p02, gf[2], fmaf(p03, gf[3], acc0[f]))));
            acc1[f] = fmaf(p10, gf[0], fmaf(p11, gf[1],
                      fmaf(p12, gf[2], fmaf(p13, gf[3], acc1[f]))));
        }
    }

    // full-wave DPP reduction -> lane 63; each (row,head) owned by ONE wave
    float ls0 = dpp_sum(l0), ls1 = dpp_sum(l1);
    float h0[16], h1[16];
    #pragma unroll
    for (int f = 0; f < 16; ++f) { h0[f] = dpp_sum(acc0[f]); h1[f] = dpp_sum(acc1[f]); }

    if (l == 63) {
        float r0 = 1.0f / ls0, r1 = 1.0f / ls1;
        #pragma unroll
        for (int f = 0; f < 16; ++f) {
            float a = h0[f]*r0; a = fmaxf(a, 0.2f*a);
            float b = h1[f]*r1; b = fmaxf(b, 0.2f*b);
            hout[i0*64 + h*16 + f] = a;
            hout[i1*64 + h*16 + f] = b;
            shh[(wid*2    )*16 + f] = a;
            shh[(wid*2 + 1)*16 + f] = b;
        }
    }
    if (t < 512) {   // filled ohm for the block's 32 rows
        int r = t >> 4, lab = t & 15;
        float v = ohm[(ib + r)*16 + lab];
        float s = v;
        #pragma unroll
        for (int m2 = 1; m2 < 16; m2 <<= 1) s += __shfl_xor(s, m2);
        ohmf[r*16 + lab] = (s == 0.f) ? 0.0625f : v;
    }
    __syncthreads();

    // deterministic centroid partial agg for this block's (32 rows, 16 dims)
    if (t < 256) {
        int lab = t >> 4, dq = t & 15;
        float s = 0.f;
        #pragma unroll 8
        for (int r = 0; r < 32; ++r)
            s = fmaf(ohmf[r*16 + lab], shh[r*16 + dq], s);
        atomicAdd(&agg[lab*64 + h*16 + dq],
                  (unsigned long long)__float2ll_rn(s * 67108864.0f));
    }
}

// ---------------------------------------------------------------------------
// k_scores: rebuild centroids per block from agg/cnt, then cdist.
// ---------------------------------------------------------------------------
__global__ __launch_bounds__(256) void k_scores(
    unsigned char* __restrict__ ws, const float* __restrict__ hout,
    float* __restrict__ scores, float* __restrict__ missing)
{
    __shared__ float cl[16*68];
    unsigned long long* cnt = (unsigned long long*)(ws + WS_CNT);
    unsigned long long* agg = (unsigned long long*)(ws + WS_AGG);
    int t = threadIdx.x;

    for (int v = t; v < 1024; v += 256) {
        int ll = v >> 6, d = v & 63;
        long long a = (long long)agg[v];
        long long c = (long long)cnt[ll];
        cl[ll*68 + d] = (c == 0) ? 0.f : ((float)a / (float)c) * 0.015625f;
    }
    if (blockIdx.x == 0 && t < 16) missing[t] = (cnt[t] == 0) ? 1.0f : 0.0f;
    __syncthreads();

    int i = blockIdx.x*16 + (t >> 4), ll = t & 15;
    float s = 0.f;
    #pragma unroll 16
    for (int d = 0; d < 64; ++d) {
        float diff = hout[i*64 + d] - cl[ll*68 + d];
        s = fmaf(diff, diff, s);
    }
    scores[i*16 + ll] = -sqrtf(s);
}

// ---------------------------------------------------------------------------
extern "C" void kernel_launch(void* const* d_in, const int* in_sizes, int n_in,
                              void* d_out, int out_size, void* d_ws, size_t ws_size,
                              hipStream_t stream)
{
    const float* x     = (const float*)d_in[0];
    const float* ohm   = (const float*)d_in[1];
    const float* Wl    = (const float*)d_in[2];
    const float* Wattn = (const float*)d_in[3];
    unsigned char* ws  = (unsigned char*)d_ws;

    float* out     = (float*)d_out;
    float* scores  = out;
    float* hout    = out + 2048*16;
    float* missing = out + 2048*16 + 2048*64;

    hipMemsetAsync(d_ws, 0, 8320, stream);           // cnt + agg
    k_proj  <<<512, 256, 0, stream>>>(x, ohm, Wl, Wattn, ws);
    k_attn  <<<256, 1024, 0, stream>>>(ohm, Wattn, ws, hout);
    k_scores<<<128, 256, 0, stream>>>(ws, hout, scores, missing);
}

// Round 21
// 53.886 us; speedup vs baseline: 1.0340x; 1.0159x over previous
//
#include <hip/hip_runtime.h>
#include <hip/hip_bf16.h>
#include <math.h>

#define C1F  0.577078016f   // 0.4 * log2(e)
#define C2F  0.865617024f   // 0.6 * log2(e)

// ws byte offsets (every read slot is written each call -> NO zero-init)
#define WS_CNTP 0                         // cntpT[16][512] f32   (32768 B)
#define WS_AGGP 32768                     // aggpT[4][256][64] f32 (262144 B)
#define WS_G    294912                    // g2[4][16][2048] f32  (524288 B)
#define WS_DCL  819200                    // dclT[4][2048] f32    (32768 B)

typedef float __attribute__((ext_vector_type(4))) f32x4;

__device__ __forceinline__ float rfl(float x) {
    return __uint_as_float(__builtin_amdgcn_readfirstlane(__float_as_uint(x)));
}

// full wave64 sum via DPP (no DS pipe); total valid in lane 63.
__device__ __forceinline__ float dpp_sum(float x) {
    float y;
    y = __int_as_float(__builtin_amdgcn_update_dpp(0, __float_as_int(x), 0x111, 0xf, 0xf, true)); x += y;
    y = __int_as_float(__builtin_amdgcn_update_dpp(0, __float_as_int(x), 0x112, 0xf, 0xf, true)); x += y;
    y = __int_as_float(__builtin_amdgcn_update_dpp(0, __float_as_int(x), 0x114, 0xf, 0xf, true)); x += y;
    y = __int_as_float(__builtin_amdgcn_update_dpp(0, __float_as_int(x), 0x118, 0xf, 0xf, true)); x += y;
    y = __int_as_float(__builtin_amdgcn_update_dpp(0, __float_as_int(x), 0x142, 0xa, 0xf, true)); x += y;
    y = __int_as_float(__builtin_amdgcn_update_dpp(0, __float_as_int(x), 0x143, 0xc, 0xf, true)); x += y;
    return x;
}

// ---------------------------------------------------------------------------
// k_proj: ohm fill + g2[h][f][j] = (pin @ Wl^T)^T + dclT[h][i] + cnt partials
// ---------------------------------------------------------------------------
__global__ __launch_bounds__(256) void k_proj(
    const float* __restrict__ x, const float* __restrict__ ohm,
    const float* __restrict__ Wl, const float* __restrict__ Wattn,
    unsigned char* __restrict__ ws)
{
    float* g2   = (float*)(ws + WS_G);
    float* dclT = (float*)(ws + WS_DCL);
    float* cntp = (float*)(ws + WS_CNTP);

    int t = threadIdx.x;
    int r = blockIdx.x * 4 + (t >> 6);
    int o = t & 63;

    f32x4 oh[4]; float rs = 0.f;
    const f32x4* ohp = (const f32x4*)&ohm[r*16];
    #pragma unroll
    for (int q = 0; q < 4; ++q) { oh[q] = ohp[q]; rs += oh[q][0]+oh[q][1]+oh[q][2]+oh[q][3]; }
    if (rs == 0.f) {
        f32x4 c = {0.0625f, 0.0625f, 0.0625f, 0.0625f};
        #pragma unroll
        for (int q = 0; q < 4; ++q) oh[q] = c;
    }

    float acc = 0.f;
    const f32x4* xp = (const f32x4*)&x[r*64];
    const f32x4* wp = (const f32x4*)&Wl[o*80];
    #pragma unroll
    for (int q = 0; q < 16; ++q) {
        f32x4 a = xp[q], b = wp[q];
        acc = fmaf(a[0],b[0],acc); acc = fmaf(a[1],b[1],acc);
        acc = fmaf(a[2],b[2],acc); acc = fmaf(a[3],b[3],acc);
    }
    #pragma unroll
    for (int q = 0; q < 4; ++q) {
        f32x4 b = wp[16+q];
        acc = fmaf(oh[q][0],b[0],acc); acc = fmaf(oh[q][1],b[1],acc);
        acc = fmaf(oh[q][2],b[2],acc); acc = fmaf(oh[q][3],b[3],acc);
    }
    // transposed store: g2[h][f][j]
    g2[(o >> 4)*32768 + (o & 15)*2048 + r] = acc;

    float dot = Wattn[o & 15] * acc;
    #pragma unroll
    for (int m2 = 1; m2 < 16; m2 <<= 1) dot += __shfl_xor(dot, m2);
    if ((o & 15) == 0) dclT[(o >> 4)*2048 + r] = C2F * dot;

    if (t < 16) {  // per-block label counts -> deterministic partial slot
        float c = 0.f;
        for (int rr = 0; rr < 4; ++rr) {
            int r2 = blockIdx.x*4 + rr; float s = 0.f;
            #pragma unroll
            for (int k = 0; k < 16; ++k) s += ohm[r2*16+k];
            c += (s == 0.f) ? 0.0625f : ohm[r2*16+t];
        }
        cntp[t*512 + blockIdx.x] = c;   // exact multiples of 1/16 (fp32-exact)
    }
}

// ---------------------------------------------------------------------------
// k_attn: whole-head LDS residency, zero main-loop barriers. grid 256 x 1024.
// block = (head h = bid>>6, 32 rows rg = bid&63). g2[h] (128KB) + dclT[h]
// (8KB) in LDS. Wave-staggered pass order (r20). Epilogue writes centroid
// partials to aggpT[h][lab*16+dq][rg] (plain stores, no atomics).
// ---------------------------------------------------------------------------
__global__ __launch_bounds__(1024, 1) void k_attn(
    const float* __restrict__ ohm, const float* __restrict__ Wattn,
    unsigned char* __restrict__ ws, float* __restrict__ hout)
{
    float* g2   = (float*)(ws + WS_G);
    float* dclT = (float*)(ws + WS_DCL);
    float* aggp = (float*)(ws + WS_AGGP);

    __shared__ float g2l[16*2048];   // 131,072 B  (f-major, stride-1 in j)
    __shared__ float djl[2048];      //   8,192 B
    __shared__ float shh[32*16];     //   2,048 B
    __shared__ float ohmf[32*16];    //   2,048 B  -> 143,360 B total

    int t = threadIdx.x, bid = blockIdx.x;
    int h  = bid >> 6;           // 4 heads x 64 row-groups
    int rg = bid & 63;
    int ib = rg * 32;            // first of 32 rows
    int wid = t >> 6, l = t & 63;
    int i0 = ib + wid*2, i1 = i0 + 1;

    const float* g2h = g2 + h*32768;
    const float* dph = dclT + h*2048;

    // ---- stage whole head into LDS (coalesced), plus SGPR constants ----
    {
        const f32x4* s4 = (const f32x4*)g2h;
        f32x4* d4 = (f32x4*)g2l;
        #pragma unroll
        for (int c = 0; c < 8; ++c) d4[t + c*1024] = s4[t + c*1024];
        if (t < 512) ((f32x4*)djl)[t] = ((const f32x4*)dph)[t];
    }
    float wv[16], gA0[16], gA1[16];
    #pragma unroll
    for (int f = 0; f < 16; ++f) {
        wv[f]  = rfl(Wattn[f]);
        gA0[f] = rfl(g2h[f*2048 + i0]);
        gA1[f] = rfl(g2h[f*2048 + i1]);
    }
    __syncthreads();   // the only pre-epilogue barrier

    float acc0[16], acc1[16];
    float l0 = 0.f, l1 = 0.f;
    #pragma unroll
    for (int f = 0; f < 16; ++f) { acc0[f] = 0.f; acc1[f] = 0.f; }

    #pragma unroll 1
    for (int pass = 0; pass < 8; ++pass) {
        int pp = (pass + wid) & 7;           // per-wave rotation (desync)
        int jb = pp*256 + 4*l;
        f32x4 G[16];
        #pragma unroll
        for (int f = 0; f < 16; ++f) G[f] = *(const f32x4*)&g2l[f*2048 + jb];
        f32x4 dj = *(const f32x4*)&djl[jb];

        float e00=0.f,e01=0.f,e02=0.f,e03=0.f;
        float e10=0.f,e11=0.f,e12=0.f,e13=0.f;
        #pragma unroll
        for (int f = 0; f < 16; ++f) {
            float a0 = gA0[f], a1 = gA1[f];
            f32x4 gf = G[f];
            e00 = fmaf(wv[f], fabsf(a0 + gf[0]), e00);   // |.| = free VOP3 mod
            e01 = fmaf(wv[f], fabsf(a0 + gf[1]), e01);
            e02 = fmaf(wv[f], fabsf(a0 + gf[2]), e02);
            e03 = fmaf(wv[f], fabsf(a0 + gf[3]), e03);
            e10 = fmaf(wv[f], fabsf(a1 + gf[0]), e10);
            e11 = fmaf(wv[f], fabsf(a1 + gf[1]), e11);
            e12 = fmaf(wv[f], fabsf(a1 + gf[2]), e12);
            e13 = fmaf(wv[f], fabsf(a1 + gf[3]), e13);
        }
        float p00 = __builtin_amdgcn_exp2f(fmaf(C1F, e00, dj[0]));
        float p01 = __builtin_amdgcn_exp2f(fmaf(C1F, e01, dj[1]));
        float p02 = __builtin_amdgcn_exp2f(fmaf(C1F, e02, dj[2]));
        float p03 = __builtin_amdgcn_exp2f(fmaf(C1F, e03, dj[3]));
        float p10 = __builtin_amdgcn_exp2f(fmaf(C1F, e10, dj[0]));
        float p11 = __builtin_amdgcn_exp2f(fmaf(C1F, e11, dj[1]));
        float p12 = __builtin_amdgcn_exp2f(fmaf(C1F, e12, dj[2]));
        float p13 = __builtin_amdgcn_exp2f(fmaf(C1F, e13, dj[3]));
        l0 += (p00 + p01) + (p02 + p03);
        l1 += (p10 + p11) + (p12 + p13);
        #pragma unroll
        for (int f = 0; f < 16; ++f) {
            f32x4 gf = G[f];
            acc0[f] = fmaf(p00, gf[0], fmaf(p01, gf[1],
                      fmaf(p02, gf[2], fmaf(p03, gf[3], acc0[f]))));
            acc1[f] = fmaf(p10, gf[0], fmaf(p11, gf[1],
                      fmaf(p12, gf[2], fmaf(p13, gf[3], acc1[f]))));
        }
    }

    // full-wave DPP reduction -> lane 63; each (row,head) owned by ONE wave
    float ls0 = dpp_sum(l0), ls1 = dpp_sum(l1);
    float h0[16], h1[16];
    #pragma unroll
    for (int f = 0; f < 16; ++f) { h0[f] = dpp_sum(acc0[f]); h1[f] = dpp_sum(acc1[f]); }

    if (l == 63) {
        float r0 = 1.0f / ls0, r1 = 1.0f / ls1;
        #pragma unroll
        for (int f = 0; f < 16; ++f) {
            float a = h0[f]*r0; a = fmaxf(a, 0.2f*a);
            float b = h1[f]*r1; b = fmaxf(b, 0.2f*b);
            hout[i0*64 + h*16 + f] = a;
            hout[i1*64 + h*16 + f] = b;
            shh[(wid*2    )*16 + f] = a;
            shh[(wid*2 + 1)*16 + f] = b;
        }
    }
    if (t < 512) {   // filled ohm for the block's 32 rows
        int r = t >> 4, lab = t & 15;
        float v = ohm[(ib + r)*16 + lab];
        float s = v;
        #pragma unroll
        for (int m2 = 1; m2 < 16; m2 <<= 1) s += __shfl_xor(s, m2);
        ohmf[r*16 + lab] = (s == 0.f) ? 0.0625f : v;
    }
    __syncthreads();

    // centroid partials -> deterministic slot (rg-contiguous for f32x4 reduce)
    if (t < 256) {
        int lab = t >> 4, dq = t & 15;
        float s = 0.f;
        #pragma unroll 8
        for (int r = 0; r < 32; ++r)
            s = fmaf(ohmf[r*16 + lab], shh[r*16 + dq], s);
        aggp[h*16384 + (lab*16 + dq)*64 + rg] = s;
    }
}

// ---------------------------------------------------------------------------
// k_scores: reduce cnt/agg partials (fixed order, deterministic), then cdist.
// ---------------------------------------------------------------------------
__global__ __launch_bounds__(256) void k_scores(
    unsigned char* __restrict__ ws, const float* __restrict__ hout,
    float* __restrict__ scores, float* __restrict__ missing)
{
    __shared__ float cl[16*68];
    __shared__ float scnt[16];
    const float* cntp = (const float*)(ws + WS_CNTP);
    const float* aggp = (const float*)(ws + WS_AGGP);
    int t = threadIdx.x;

    if (t < 128) {   // cnt[lab] = sum of 512 partials (exact; fixed tree)
        int lab = t >> 3, seg = t & 7;
        const f32x4* p = (const f32x4*)&cntp[lab*512 + seg*64];
        float c = 0.f;
        #pragma unroll
        for (int q = 0; q < 16; ++q) { f32x4 v = p[q]; c += (v[0]+v[1])+(v[2]+v[3]); }
        #pragma unroll
        for (int m2 = 1; m2 < 8; m2 <<= 1) c += __shfl_xor(c, m2);
        if (seg == 0) scnt[lab] = c;
    }
    __syncthreads();

    for (int v = t; v < 1024; v += 256) {   // cl[lab][d] from 64 partials
        int lab = v >> 6, d = v & 63;
        int h = d >> 4, dq = d & 15;
        const f32x4* p = (const f32x4*)&aggp[h*16384 + (lab*16 + dq)*64];
        float a = 0.f;
        #pragma unroll
        for (int q = 0; q < 16; ++q) { f32x4 x4 = p[q]; a += (x4[0]+x4[1])+(x4[2]+x4[3]); }
        float c = scnt[lab];
        cl[lab*68 + d] = (c == 0.f) ? 0.f : a / c;
    }
    if (blockIdx.x == 0 && t < 16) missing[t] = (scnt[t] == 0.f) ? 1.0f : 0.0f;
    __syncthreads();

    int i = blockIdx.x*16 + (t >> 4), ll = t & 15;
    float s = 0.f;
    #pragma unroll 16
    for (int d = 0; d < 64; ++d) {
        float diff = hout[i*64 + d] - cl[ll*68 + d];
        s = fmaf(diff, diff, s);
    }
    scores[i*16 + ll] = -sqrtf(s);
}

// ---------------------------------------------------------------------------
extern "C" void kernel_launch(void* const* d_in, const int* in_sizes, int n_in,
                              void* d_out, int out_size, void* d_ws, size_t ws_size,
                              hipStream_t stream)
{
    const float* x     = (const float*)d_in[0];
    const float* ohm   = (const float*)d_in[1];
    const float* Wl    = (const float*)d_in[2];
    const float* Wattn = (const float*)d_in[3];
    unsigned char* ws  = (unsigned char*)d_ws;

    float* out     = (float*)d_out;
    float* scores  = out;
    float* hout    = out + 2048*16;
    float* missing = out + 2048*16 + 2048*64;

    // no memset: every ws slot read downstream is written unconditionally
    k_proj  <<<512, 256, 0, stream>>>(x, ohm, Wl, Wattn, ws);
    k_attn  <<<256, 1024, 0, stream>>>(ohm, Wattn, ws, hout);
    k_scores<<<128, 256, 0, stream>>>(ws, hout, scores, missing);
}